// Round 10
// baseline (90.566 us; speedup 1.0000x reference)
//
#include <hip/hip_runtime.h>
#include <math.h>

#define BLOCK 256
#define PPT 8               // rows per thread -> 2048 rows per block
#define RPB (BLOCK * PPT)   // 2048
#define CLEN 32             // cols per LDS tile (34 KB LDS -> 4 blocks/CU)
#define CTILES 4            // col tiles swept per block -> 128 cols per block
#define SPAD 257            // scmin padded stride (bank = (c+i)%32, conflict-free)
#define FBLOCKS 128

// ---- order-preserving float <-> uint key (works for negatives) ----
__device__ __forceinline__ unsigned f2key(float f) {
    unsigned b = __float_as_uint(f);
    return b ^ ((b & 0x80000000u) ? 0xFFFFFFFFu : 0x80000000u);
}
__device__ __forceinline__ float key2f(unsigned k) {
    unsigned b = k ^ ((k & 0x80000000u) ? 0x80000000u : 0xFFFFFFFFu);
    return __uint_as_float(b);
}
__device__ __forceinline__ float min3f(float a, float b, float c) {
    return fminf(fminf(a, b), c);   // -> v_min3_f32
}

// Shared-d tile kernel: block = (2048 rows of array1) x (4 x 32 cols of array2)
// for one batch. Computes full d = a^2 + b^2 - 2ab ONCE per pair (fma chain
// seeded with t = a2 + b.w so both direction-constants are inside the min):
//   - row mins (dist1): register accumulators across ALL 4 col-tiles,
//     ONE atomicMin per row per block (R9 showed 33 MB of atomic writeback
//     at 4096 blocks; CTILES=4 cuts row-atomics 4x)
//   - col mins (dist2): per-thread min3-fold over its 8 rows -> scmin[col][tid],
//     block tree-reduce per tile, one atomicMin per col
// R10 reverts R9's full-unroll + launch_bounds(,4) (VGPR 88->52 register
// starvation regressed the kernel 38->50 us); rolled jj loop, compiler-chosen
// VGPR budget. Occupancy is LDS-capped at 4 blocks/CU either way.
__global__ __launch_bounds__(BLOCK) void chamfer_tile_kernel(
    const float* __restrict__ arr1, const float* __restrict__ arr2,
    int N, int M,
    unsigned* __restrict__ rkey, unsigned* __restrict__ ckey,
    float* __restrict__ out)
{
    const int b  = blockIdx.z;
    const int r0 = blockIdx.x * RPB;             // row offset within batch
    const int c0 = blockIdx.y * (CLEN * CTILES); // col offset within batch

    // Zero the output accumulator exactly once (finalize is a later dispatch).
    if (blockIdx.x == 0 && blockIdx.y == 0 && blockIdx.z == 0 && threadIdx.x == 0)
        out[0] = 0.0f;

    __shared__ float4 sb[CLEN];
    __shared__ float scmin[CLEN][SPAD];
    __shared__ float cred[8][CLEN];

    // Row points in registers (+ their squared norms)
    float ax[PPT], ay[PPT], az[PPT], a2[PPT], mn[PPT];
    const float* abase = arr1 + ((size_t)b * N + r0) * 3;
#pragma unroll
    for (int k = 0; k < PPT; ++k) {
        int idx = threadIdx.x + k * BLOCK;
        float x = abase[idx * 3 + 0];
        float y = abase[idx * 3 + 1];
        float z = abase[idx * 3 + 2];
        ax[k] = x; ay[k] = y; az[k] = z;
        a2[k] = __builtin_fmaf(x, x, __builtin_fmaf(y, y, z * z));
        mn[k] = __builtin_inff();
    }

    for (int t = 0; t < CTILES; ++t) {
        const int c = c0 + t * CLEN;

        // Stage this tile's col points, prescaled: (-2x, -2y, -2z, |b|^2).
        // (sb's prior-tile readers all finished before the last tail sync.)
        if (threadIdx.x < CLEN) {
            const float* p = arr2 + ((size_t)b * M + c + threadIdx.x) * 3;
            float x = p[0], y = p[1], z = p[2];
            sb[threadIdx.x] = make_float4(-2.0f * x, -2.0f * y, -2.0f * z,
                                          __builtin_fmaf(x, x, __builtin_fmaf(y, y, z * z)));
        }
        __syncthreads();

        // Inner scan: 2 cols per step. Per (2j, k): 2 add + 6 fma + 1 min3(row);
        // col fold 2x4 min3 -> ~5.1 slots per pair, serving both directions.
        for (int jj = 0; jj < CLEN; jj += 2) {
            float4 b0 = sb[jj];
            float4 b1 = sb[jj + 1];
            float d0a[PPT], d1a[PPT];
#pragma unroll
            for (int k = 0; k < PPT; ++k) {
                float t0 = a2[k] + b0.w;
                float t1 = a2[k] + b1.w;
                float d0 = __builtin_fmaf(b0.x, ax[k],
                           __builtin_fmaf(b0.y, ay[k],
                           __builtin_fmaf(b0.z, az[k], t0)));
                float d1 = __builtin_fmaf(b1.x, ax[k],
                           __builtin_fmaf(b1.y, ay[k],
                           __builtin_fmaf(b1.z, az[k], t1)));
                mn[k] = min3f(mn[k], d0, d1);   // row min
                d0a[k] = d0;
                d1a[k] = d1;
            }
            // Col partial: min3-fold this thread's 8 rows for each of 2 cols
            float cm0 = fminf(min3f(min3f(min3f(d0a[0], d0a[1], d0a[2]),
                                          d0a[3], d0a[4]),
                                    d0a[5], d0a[6]),
                              d0a[7]);
            float cm1 = fminf(min3f(min3f(min3f(d1a[0], d1a[1], d1a[2]),
                                          d1a[3], d1a[4]),
                                    d1a[5], d1a[6]),
                              d1a[7]);
            scmin[jj][threadIdx.x]     = cm0;   // bank (jj+tid)%32: 2-way, free
            scmin[jj + 1][threadIdx.x] = cm1;
        }
        __syncthreads();

        // Col reduce stage 1: thread (cc = tid&31, s = tid>>5) tree-reduces
        // scmin[cc][s*32 .. s*32+31].  bank = (cc+i)%32 -> <=2-way (free).
        {
            int cc = threadIdx.x & 31, s = threadIdx.x >> 5;
            const float* row = &scmin[cc][s * 32];
            float v0 = row[0], v1 = row[1];
#pragma unroll
            for (int i = 2; i < 32; i += 2) {
                v0 = fminf(v0, row[i]);
                v1 = fminf(v1, row[i + 1]);
            }
            cred[s][cc] = fminf(v0, v1);
        }
        __syncthreads();
        // Stage 2: 32 threads fold the 8 segment partials, one atomic per col.
        // (Runs concurrently with nothing that touches cred until next stage-1,
        //  which is 2 syncs away.)
        if (threadIdx.x < CLEN) {
            float v = fminf(min3f(min3f(min3f(cred[0][threadIdx.x],
                                              cred[1][threadIdx.x],
                                              cred[2][threadIdx.x]),
                                        cred[3][threadIdx.x],
                                        cred[4][threadIdx.x]),
                                  cred[5][threadIdx.x],
                                  cred[6][threadIdx.x]),
                            cred[7][threadIdx.x]);
            atomicMin(&ckey[(size_t)b * M + c + threadIdx.x], f2key(v));
        }
    }

    // Row partials -> ONE atomicMin per row per block (after all 4 col tiles)
    unsigned* rk = rkey + (size_t)b * N + r0;
#pragma unroll
    for (int k = 0; k < PPT; ++k)
        atomicMin(&rk[threadIdx.x + k * BLOCK], f2key(mn[k]));
}

// Finalize: keys already hold full d mins (a^2 and b^2 included) -> just a
// weighted sum of 64k values (0.26 MB), one atomicAdd per block.
__global__ __launch_bounds__(256) void chamfer_finalize_kernel(
    const unsigned* __restrict__ rkey, const unsigned* __restrict__ ckey,
    int BN, int BM, float* __restrict__ out)
{
    const float wA = 1.0f / (float)BN;
    const float wB = 1.0f / (float)BM;
    const int stride = 256 * FBLOCKS;

    float s = 0.0f;
    for (int i = blockIdx.x * 256 + threadIdx.x; i < BN; i += stride)
        s += wA * key2f(rkey[i]);
    for (int i = blockIdx.x * 256 + threadIdx.x; i < BM; i += stride)
        s += wB * key2f(ckey[i]);

#pragma unroll
    for (int off = 32; off > 0; off >>= 1)
        s += __shfl_down(s, off, 64);

    __shared__ float wsum[4];
    int lane = threadIdx.x & 63, wv = threadIdx.x >> 6;
    if (lane == 0) wsum[wv] = s;
    __syncthreads();
    if (threadIdx.x == 0)
        atomicAdd(out, wsum[0] + wsum[1] + wsum[2] + wsum[3]);
}

extern "C" void kernel_launch(void* const* d_in, const int* in_sizes, int n_in,
                              void* d_out, int out_size, void* d_ws, size_t ws_size,
                              hipStream_t stream)
{
    const float* arr1 = (const float*)d_in[0];
    const float* arr2 = (const float*)d_in[1];
    float* out = (float*)d_out;

    const int Bb = 4;
    const int N = in_sizes[0] / (Bb * 3);   // 8192
    const int M = in_sizes[1] / (Bb * 3);   // 8192
    const int BN = Bb * N, BM = Bb * M;

    unsigned* rkey = (unsigned*)d_ws;        // [BN]
    unsigned* ckey = rkey + BN;              // [BM]

    // Init all min-keys to 0xFFFFFFFF (max) — ws is poisoned 0xAA each launch.
    hipMemsetAsync(rkey, 0xFF, (size_t)(BN + BM) * sizeof(unsigned), stream);

    dim3 grid(N / RPB, M / (CLEN * CTILES), Bb);   // (4, 64, 4) = 1024 blocks
    chamfer_tile_kernel<<<grid, BLOCK, 0, stream>>>(arr1, arr2, N, M,
                                                    rkey, ckey, out);

    chamfer_finalize_kernel<<<FBLOCKS, 256, 0, stream>>>(rkey, ckey, BN, BM, out);
}